// Round 3
// baseline (530.102 us; speedup 1.0000x reference)
//
#include <hip/hip_runtime.h>
#include <hip/hip_bf16.h>

#define H  1024
#define L  4096
#define V  50257

// workspace layout (floats)
#define OFF_QW     0                    // 1024   query @ Wq (direct store)
#define OFF_SCORES 1024                 // 4096   raw scores (atomic)
#define OFF_X      5120                 // 2048   x = [context (atomic) | emb_relu]
#define OFF_GI0    7168                 // 3072   prep: emb-half partial; gi0 final
#define OFF_GH0    10240                // 3072
#define OFF_GI1    13312                // 3072
#define OFF_GH1    16384                // 3072
#define OFF_LOGITS 19456                // V      (atomic)
#define OFF_PMAX   (OFF_LOGITS + V)     // 197 lsm max partials
#define OFF_PSUM   (OFF_PMAX + 256)     // 197 lsm sum partials
#define OFF_WKT_BYTES   283008          // bf16 WkT[1024][1024] = 2 MB
#define OFF_ENC16_BYTES 2380160         // bf16 enc16[4096][1024] = 8 MB

typedef __bf16 bf8   __attribute__((ext_vector_type(8)));
typedef float  f32x16 __attribute__((ext_vector_type(16)));

__device__ inline unsigned int pack_bf16x2(float lo, float hi) {
    unsigned int ulo = __builtin_bit_cast(unsigned int, lo);
    unsigned int uhi = __builtin_bit_cast(unsigned int, hi);
    return ((uhi + 0x8000u) & 0xFFFF0000u) | ((ulo + 0x8000u) >> 16);
}
__device__ inline unsigned short cvt_bf16(float f) {
    unsigned int u = __builtin_bit_cast(unsigned int, f);
    return (unsigned short)((u + 0x8000u) >> 16);
}
__device__ inline float fast_tanh(float x) {
    float e = __expf(-2.f * fabsf(x));
    float t = (1.f - e) / (1.f + e);
    return copysignf(t, x);
}
__device__ inline float fast_sigmoid(float x) {
    return 1.f / (1.f + __expf(-x));
}

// ============ prep: zero | embed+relu | qW | WkT | enc16 | gh0/gh1 | gi0emb ===
// virtual blocks:
//  [0,16)      zero SCORES+X[0:H] (contig 1024..6144) and LOGITS
//  [16,20)     embed+relu -> X[H:2H)
//  [20,36)     qW = q @ Wq (LDS-reduced, direct store)
//  [36,1060)   WkT bf16 transpose tiles
//  [1060,2084) enc -> bf16 enc16
//  [2084,2852) gh0   [2852,3620) gh1
//  [3620,4388) gi0 emb-half partial (+bih0) -> OFF_GI0
__global__ __launch_bounds__(256) void k_prep(const int* __restrict__ tok,
                                              const float* __restrict__ emb,
                                              const float* __restrict__ hid,
                                              const float* __restrict__ Wq,
                                              const float* __restrict__ Wk,
                                              const float* __restrict__ enc,
                                              const float* __restrict__ Whh0,
                                              const float* __restrict__ bhh0,
                                              const float* __restrict__ Whh1,
                                              const float* __restrict__ bhh1,
                                              const float* __restrict__ Wih0,
                                              const float* __restrict__ bih0,
                                              float* __restrict__ ws,
                                              unsigned short* __restrict__ wkT,
                                              unsigned short* __restrict__ enc16) {
    __shared__ float tile[32][33];
    __shared__ float er[H];
    __shared__ float part[4][64];
    const int b = blockIdx.x, t = threadIdx.x;
    if (b < 16) {
        // zero: span A = ws[1024..6144) (1280 f4), span B = logits (12564 f4 + 1)
        const int NF4 = 1280 + 12564;
        float4 z = {0.f, 0.f, 0.f, 0.f};
        for (int i = b * 256 + t; i < NF4; i += 16 * 256) {
            if (i < 1280) *(float4*)(ws + OFF_SCORES + 4 * i) = z;
            else          *(float4*)(ws + OFF_LOGITS + 4 * (i - 1280)) = z;
        }
        if (b == 0 && t == 0) ws[OFF_LOGITS + 50256] = 0.f;
    } else if (b < 20) {
        int j = (b - 16) * 256 + t;
        float v = emb[(size_t)tok[0] * H + j];
        ws[OFF_X + H + j] = fmaxf(v, 0.f);
    } else if (b < 36) {
        // qW[j0+jl] = sum_i q[i]*Wq[i][j0+jl]; lanes along j (coalesced),
        // waves along i-chunks of 256, LDS reduce, direct store.
        int j0 = (b - 20) * 64, jl = t & 63, q = t >> 6;
        const float* qv = hid + H;
        float acc = 0.f;
#pragma unroll 8
        for (int i = q * 256; i < q * 256 + 256; ++i)
            acc += qv[i] * Wq[(size_t)i * H + j0 + jl];
        part[q][jl] = acc;
        __syncthreads();
        if (t < 64)
            ws[OFF_QW + j0 + t] = part[0][t] + part[1][t] + part[2][t] + part[3][t];
    } else if (b < 1060) {
        int tt = b - 36;              // 32x32 grid of 32x32 tiles
        int tk = tt & 31, tn = tt >> 5;
        int c = t & 31, r0 = t >> 5;
#pragma unroll
        for (int rr = 0; rr < 4; ++rr) {
            int r = r0 + rr * 8;
            tile[r][c] = Wk[(size_t)(tk * 32 + r) * H + tn * 32 + c];
        }
        __syncthreads();
#pragma unroll
        for (int rr = 0; rr < 4; ++rr) {
            int rn = r0 + rr * 8;
            wkT[(size_t)(tn * 32 + rn) * H + tk * 32 + c] = cvt_bf16(tile[c][rn]);
        }
    } else if (b < 2084) {
        // enc[4 rows] fp32 -> bf16
        int row = (b - 1060) * 4 + (t >> 6);
        int c0 = (t & 63) * 16;
        const float* src = enc + (size_t)row * H + c0;
        float4 f0 = *(const float4*)(src);
        float4 f1 = *(const float4*)(src + 4);
        float4 f2 = *(const float4*)(src + 8);
        float4 f3 = *(const float4*)(src + 12);
        uint4 u0, u1;
        u0.x = pack_bf16x2(f0.x, f0.y); u0.y = pack_bf16x2(f0.z, f0.w);
        u0.z = pack_bf16x2(f1.x, f1.y); u0.w = pack_bf16x2(f1.z, f1.w);
        u1.x = pack_bf16x2(f2.x, f2.y); u1.y = pack_bf16x2(f2.z, f2.w);
        u1.z = pack_bf16x2(f3.x, f3.y); u1.w = pack_bf16x2(f3.z, f3.w);
        *(uint4*)(enc16 + (size_t)row * H + c0)     = u0;
        *(uint4*)(enc16 + (size_t)row * H + c0 + 8) = u1;
    } else if (b < 3620) {
        // gh = Whh @ h + bhh (one wave per row)
        bool l1 = (b >= 2852);
        int row  = (b - (l1 ? 2852 : 2084)) * 4 + (t >> 6);
        int lane = t & 63;
        const float*  W  = l1 ? Whh1 : Whh0;
        const float*  bi = l1 ? bhh1 : bhh0;
        const float4* hv = (const float4*)(l1 ? hid + H : hid);
        const float4* Wr = (const float4*)(W + (size_t)row * H);
        float acc = 0.f;
#pragma unroll
        for (int c = lane; c < H / 4; c += 64) {
            float4 w = Wr[c], x = hv[c];
            acc += w.x * x.x + w.y * x.y + w.z * x.z + w.w * x.w;
        }
#pragma unroll
        for (int off = 32; off; off >>= 1) acc += __shfl_down(acc, off);
        if (lane == 0) ws[(l1 ? OFF_GH1 : OFF_GH0) + row] = acc + bi[row];
    } else {
        // gi0 emb-half partial: Wih0[row][H:2H) @ relu(emb[tok]) + bih0[row]
        int row = (b - 3620) * 4 + (t >> 6);
        int lane = t & 63;
        int tk = tok[0];
        for (int j = t; j < H; j += 256) er[j] = fmaxf(emb[(size_t)tk * H + j], 0.f);
        __syncthreads();
        const float4* Wr = (const float4*)(Wih0 + (size_t)row * (2 * H) + H);
        const float4* e4 = (const float4*)er;
        float acc = 0.f;
#pragma unroll
        for (int c = lane; c < H / 4; c += 64) {
            float4 w = Wr[c], x = e4[c];
            acc += w.x * x.x + w.y * x.y + w.z * x.z + w.w * x.w;
        }
#pragma unroll
        for (int off = 32; off; off >>= 1) acc += __shfl_down(acc, off);
        if (lane == 0) ws[OFF_GI0 + row] = acc + bih0[row];
    }
}

// ============ scores GEMM: all-bf16 MFMA, tile 64x128, K-step 32 ============
// A = enc16 (pre-converted), B = wkT. Epilogue: tanh(+qW)*wv reduced over n.
__global__ __launch_bounds__(256) void k_gemm_scores(const unsigned short* __restrict__ enc16,
                                                     const unsigned short* __restrict__ wkT,
                                                     const float* __restrict__ wv,
                                                     float* __restrict__ ws) {
    __shared__ unsigned short As[64][40];   // [m][k] bf16, +8 pad
    __shared__ unsigned short Bs[128][40];  // [n][k] bf16
    const int t = threadIdx.x, lane = t & 63, w = t >> 6;
    const int m0 = blockIdx.x * 64, n0 = blockIdx.y * 128;

    f32x16 acc0 = {}, acc1 = {};

    const int ar = t >> 2, ak = (t & 3) * 8;      // A: 64x32 bf16, 1 uint4/thread
    const int bn = t >> 1, bkh = (t & 1) * 16;    // B: 128x32 bf16, 2 uint4/thread

    const int r0 = (w & 1) * 32, c0 = (w >> 1) * 64;
    const int mrow = r0 + (lane & 31);
    const int nrow0 = c0 + (lane & 31), nrow1 = nrow0 + 32;

    for (int k0 = 0; k0 < H; k0 += 32) {
        uint4 a   = *(const uint4*)(enc16 + (size_t)(m0 + ar) * H + k0 + ak);
        uint4 wb0 = *(const uint4*)(wkT + (size_t)(n0 + bn) * H + k0 + bkh);
        uint4 wb1 = *(const uint4*)(wkT + (size_t)(n0 + bn) * H + k0 + bkh + 8);
        __syncthreads();   // previous-iter LDS reads done before overwrite
        *(uint4*)&As[ar][ak] = a;
        *(uint4*)&Bs[bn][bkh] = wb0;
        *(uint4*)&Bs[bn][bkh + 8] = wb1;
        __syncthreads();
#pragma unroll
        for (int kk = 0; kk < 2; ++kk) {
            int kb = kk * 16 + (lane >> 5) * 8;
            bf8 av = *(const bf8*)&As[mrow][kb];
            bf8 b0 = *(const bf8*)&Bs[nrow0][kb];
            bf8 b1 = *(const bf8*)&Bs[nrow1][kb];
            acc0 = __builtin_amdgcn_mfma_f32_32x32x16_bf16(av, b0, acc0, 0, 0, 0);
            acc1 = __builtin_amdgcn_mfma_f32_32x32x16_bf16(av, b1, acc1, 0, 0, 0);
        }
    }

    // epilogue: s[l] += sum_n tanh(acc+qW[n])*wv[n]
    const int n_a = n0 + nrow0, n_b = n0 + nrow1;
    float qwa = ws[OFF_QW + n_a], qwb = ws[OFF_QW + n_b];
    float wva = wv[n_a], wvb = wv[n_b];
    const int rbase = m0 + r0 + 4 * (lane >> 5);
#pragma unroll
    for (int reg = 0; reg < 16; ++reg) {
        float s = fast_tanh(acc0[reg] + qwa) * wva + fast_tanh(acc1[reg] + qwb) * wvb;
#pragma unroll
        for (int msk = 1; msk < 32; msk <<= 1) s += __shfl_xor(s, msk);
        if ((lane & 31) == 0) {
            int l = rbase + (reg & 3) + 8 * (reg >> 2);
            atomicAdd(&ws[OFF_SCORES + l], s);
        }
    }
}

// ============ context with inline softmax (probs staged in LDS) ====
// grid (4 h-blocks, 32 l-splits of 128)
__global__ __launch_bounds__(256) void k_context(const float* __restrict__ enc,
                                                 float* __restrict__ ws) {
    __shared__ float red[4];
    __shared__ float ps[128];
    const int t = threadIdx.x;
    const float* sc = ws + OFF_SCORES;

    float m = -1e30f;
#pragma unroll
    for (int i = 0; i < 16; ++i) m = fmaxf(m, sc[t + i * 256]);
#pragma unroll
    for (int msk = 1; msk < 64; msk <<= 1) m = fmaxf(m, __shfl_xor(m, msk));
    if ((t & 63) == 0) red[t >> 6] = m;
    __syncthreads();
    m = fmaxf(fmaxf(red[0], red[1]), fmaxf(red[2], red[3]));
    __syncthreads();

    float s = 0.f;
#pragma unroll
    for (int i = 0; i < 16; ++i) s += __expf(sc[t + i * 256] - m);
#pragma unroll
    for (int msk = 1; msk < 64; msk <<= 1) s += __shfl_xor(s, msk);
    if ((t & 63) == 0) red[t >> 6] = s;
    __syncthreads();
    float inv = 1.f / (red[0] + red[1] + red[2] + red[3]);

    const int l0 = blockIdx.y * 128;
    if (t < 128) ps[t] = __expf(sc[l0 + t] - m) * inv;
    __syncthreads();

    const int h = blockIdx.x * 256 + t;
    float acc = 0.f;
#pragma unroll 4
    for (int l = 0; l < 128; ++l)
        acc += ps[l] * enc[(size_t)(l0 + l) * H + h];
    atomicAdd(&ws[OFF_X + h], acc);
}

// ============ gi0: context half + stored emb partial (768 blocks) ============
__global__ __launch_bounds__(256) void k_gi0(const float* __restrict__ Wih,
                                             float* __restrict__ ws) {
    int row = blockIdx.x * 4 + (threadIdx.x >> 6);
    int lane = threadIdx.x & 63;
    const float4* Wr = (const float4*)(Wih + (size_t)row * (2 * H));   // ctx half
    const float4* v4 = (const float4*)(ws + OFF_X);
    float acc = 0.f;
#pragma unroll
    for (int c = lane; c < H / 4; c += 64) {
        float4 w = Wr[c], xx = v4[c];
        acc += w.x * xx.x + w.y * xx.y + w.z * xx.z + w.w * xx.w;
    }
#pragma unroll
    for (int off = 32; off; off >>= 1) acc += __shfl_down(acc, off);
    if (lane == 0) ws[OFF_GI0 + row] += acc;    // partial (emb half + bias) stored by prep
}

// ============ combine0 -> h0n ; gi1 = Wih1 @ h0n (768 blocks) ============
__global__ __launch_bounds__(256) void k_gi1(const float* __restrict__ Wih,
                                             const float* __restrict__ bih,
                                             const float* __restrict__ gi0,
                                             const float* __restrict__ gh0,
                                             const float* __restrict__ hid,
                                             float* __restrict__ h0n_out,
                                             float* __restrict__ gi) {
    __shared__ float xs[H];
    const int b = blockIdx.x, t = threadIdx.x, lane = t & 63;
#pragma unroll
    for (int jj = 0; jj < 4; ++jj) {
        int j = t + jj * 256;
        float r = fast_sigmoid(gi0[j] + gh0[j]);
        float z = fast_sigmoid(gi0[H + j] + gh0[H + j]);
        float n = fast_tanh(gi0[2 * H + j] + r * gh0[2 * H + j]);
        float h0 = (1.f - z) * n + z * hid[j];
        xs[j] = h0;
        if (b == 0) h0n_out[j] = h0;
    }
    __syncthreads();
    int row = b * 4 + (t >> 6);
    const float4* Wr = (const float4*)(Wih + (size_t)row * H);
    float acc = 0.f;
#pragma unroll
    for (int c = lane; c < H / 4; c += 64) {
        float4 w = Wr[c];
        float4 xx = *(const float4*)&xs[c * 4];
        acc += w.x * xx.x + w.y * xx.y + w.z * xx.z + w.w * xx.w;
    }
#pragma unroll
    for (int off = 32; off; off >>= 1) acc += __shfl_down(acc, off);
    if (lane == 0) gi[row] = acc + bih[row];
}

// ============ combine1 -> h1n ; logits (4 ILP streams) ============
// grid (50 v-blocks of 1024, 16 k-splits of 64)
__global__ __launch_bounds__(256) void k_logits(const float* __restrict__ Wd,
                                                const float* __restrict__ bd,
                                                const float* __restrict__ gi1,
                                                const float* __restrict__ gh1,
                                                const float* __restrict__ hid,
                                                float* __restrict__ h1n_out,
                                                float* __restrict__ ws) {
    __shared__ float h1s[H];
    const int t = threadIdx.x;
#pragma unroll
    for (int jj = 0; jj < 4; ++jj) {
        int j = t + jj * 256;
        float r = fast_sigmoid(gi1[j] + gh1[j]);
        float z = fast_sigmoid(gi1[H + j] + gh1[H + j]);
        float n = fast_tanh(gi1[2 * H + j] + r * gh1[2 * H + j]);
        float h1 = (1.f - z) * n + z * hid[H + j];
        h1s[j] = h1;
        if (blockIdx.x == 0 && blockIdx.y == 0) h1n_out[j] = h1;
    }
    __syncthreads();
    const int v0 = blockIdx.x * 1024, k0 = blockIdx.y * 64;
    const int va = v0 + t, vb = va + 256, vc = va + 512, vd = va + 768;
    const int vca = va < V ? va : V - 1;
    const int vcb = vb < V ? vb : V - 1;
    const int vcc = vc < V ? vc : V - 1;
    const int vcd = vd < V ? vd : V - 1;
    float a0 = 0.f, a1 = 0.f, a2 = 0.f, a3 = 0.f;
    const float* Wp = Wd + (size_t)k0 * V;
#pragma unroll 8
    for (int k = 0; k < 64; ++k) {           // 4 streams -> 32 loads in flight
        float xk = h1s[k0 + k];
        const float* row = Wp + (size_t)k * V;
        a0 += xk * row[vca];
        a1 += xk * row[vcb];
        a2 += xk * row[vcc];
        a3 += xk * row[vcd];
    }
    if (va < V) atomicAdd(&ws[OFF_LOGITS + va], a0 + (k0 == 0 ? bd[va] : 0.f));
    if (vb < V) atomicAdd(&ws[OFF_LOGITS + vb], a1 + (k0 == 0 ? bd[vb] : 0.f));
    if (vc < V) atomicAdd(&ws[OFF_LOGITS + vc], a2 + (k0 == 0 ? bd[vc] : 0.f));
    if (vd < V) atomicAdd(&ws[OFF_LOGITS + vd], a3 + (k0 == 0 ? bd[vd] : 0.f));
}

// ============ log_softmax stage 1: per-block (max, expsum) partials ======
__global__ __launch_bounds__(256) void k_lsm1(const float* __restrict__ lg,
                                              float* __restrict__ ws) {
    __shared__ float red[4];
    const int b = blockIdx.x, t = threadIdx.x;
    const int g = b * 256 + t;
    float x = (g < V) ? lg[g] : -1e30f;

    float m = x;
#pragma unroll
    for (int msk = 1; msk < 64; msk <<= 1) m = fmaxf(m, __shfl_xor(m, msk));
    if ((t & 63) == 0) red[t >> 6] = m;
    __syncthreads();
    m = fmaxf(fmaxf(red[0], red[1]), fmaxf(red[2], red[3]));
    __syncthreads();

    float s = (g < V) ? __expf(x - m) : 0.f;
#pragma unroll
    for (int msk = 1; msk < 64; msk <<= 1) s += __shfl_xor(s, msk);
    if ((t & 63) == 0) red[t >> 6] = s;
    __syncthreads();
    if (t == 0) {
        ws[OFF_PMAX + b] = m;
        ws[OFF_PSUM + b] = red[0] + red[1] + red[2] + red[3];
    }
}

// ============ log_softmax stage 2: reduce partials, write out ============
__global__ __launch_bounds__(256) void k_lsm2(const float* __restrict__ lg,
                                              const float* __restrict__ ws,
                                              float* __restrict__ out) {
    __shared__ float red[4];
    const int b = blockIdx.x, t = threadIdx.x;

    float pm = (t < 197) ? ws[OFF_PMAX + t] : -1e30f;
    float m = pm;
#pragma unroll
    for (int msk = 1; msk < 64; msk <<= 1) m = fmaxf(m, __shfl_xor(m, msk));
    if ((t & 63) == 0) red[t >> 6] = m;
    __syncthreads();
    m = fmaxf(fmaxf(red[0], red[1]), fmaxf(red[2], red[3]));
    __syncthreads();

    float s = (t < 197) ? ws[OFF_PSUM + t] * __expf(pm - m) : 0.f;
#pragma unroll
    for (int msk = 1; msk < 64; msk <<= 1) s += __shfl_xor(s, msk);
    if ((t & 63) == 0) red[t >> 6] = s;
    __syncthreads();
    float lse = m + logf(red[0] + red[1] + red[2] + red[3]);

    const int g = b * 256 + t;
    if (g < V) out[g] = lg[g] - lse;
}

extern "C" void kernel_launch(void* const* d_in, const int* in_sizes, int n_in,
                              void* d_out, int out_size, void* d_ws, size_t ws_size,
                              hipStream_t stream) {
    const int*   tok  = (const int*)d_in[0];
    const float* hid  = (const float*)d_in[1];   // [2,1,H]
    const float* enc  = (const float*)d_in[2];   // [L,H]
    const float* emb  = (const float*)d_in[3];   // [V,H]
    const float* Wq   = (const float*)d_in[4];
    const float* Wk   = (const float*)d_in[5];
    const float* wv   = (const float*)d_in[6];
    const float* Wih0 = (const float*)d_in[7];
    const float* Whh0 = (const float*)d_in[8];
    const float* bih0 = (const float*)d_in[9];
    const float* bhh0 = (const float*)d_in[10];
    const float* Wih1 = (const float*)d_in[11];
    const float* Whh1 = (const float*)d_in[12];
    const float* bih1 = (const float*)d_in[13];
    const float* bhh1 = (const float*)d_in[14];
    const float* Wd   = (const float*)d_in[15];  // [H,V]
    const float* bd   = (const float*)d_in[16];
    float* out = (float*)d_out;                  // [V logp][H h0n][H h1n]
    float* ws  = (float*)d_ws;
    unsigned short* wkT   = (unsigned short*)((char*)d_ws + OFF_WKT_BYTES);
    unsigned short* enc16 = (unsigned short*)((char*)d_ws + OFF_ENC16_BYTES);

    k_prep<<<4388, 256, 0, stream>>>(tok, emb, hid, Wq, Wk, enc,
                                     Whh0, bhh0, Whh1, bhh1, Wih0, bih0,
                                     ws, wkT, enc16);
    k_gemm_scores<<<dim3(L / 64, H / 128), 256, 0, stream>>>(enc16, wkT, wv, ws);
    k_context<<<dim3(4, 32), 256, 0, stream>>>(enc, ws);
    k_gi0<<<768, 256, 0, stream>>>(Wih0, ws);
    k_gi1<<<768, 256, 0, stream>>>(Wih1, bih1, ws + OFF_GI0, ws + OFF_GH0,
                                   hid, out + V, ws + OFF_GI1);
    k_logits<<<dim3(50, 16), 256, 0, stream>>>(Wd, bd, ws + OFF_GI1, ws + OFF_GH1,
                                               hid, out + V + H, ws);
    k_lsm1<<<197, 256, 0, stream>>>(ws + OFF_LOGITS, ws);
    k_lsm2<<<197, 256, 0, stream>>>(ws + OFF_LOGITS, ws, out);
}